// Round 7
// baseline (329.755 us; speedup 1.0000x reference)
//
#include <hip/hip_runtime.h>
#include <hip/hip_bf16.h>
#include <math.h>

// Problem constants
#define B_    8
#define C_    64
#define H_    64
#define W_    64
#define NUM_EMBED 8192
#define DIMS  64
#define N_TOK (B_ * H_ * W_)           // 32768
#define N_ELEM (B_ * C_ * H_ * W_)     // 2097152

typedef short v8s  __attribute__((ext_vector_type(8)));   // 8 bf16 = 4 VGPR
typedef float v16f __attribute__((ext_vector_type(16)));  // 32x32 MFMA acc

#define MARGIN 0.0095f  // rigorous bf16 bound 2*2^-8 = 0.0078, + headroom

// ---- helpers ---------------------------------------------------------------
__device__ __forceinline__ short bf16_rne(float x) {
    unsigned u = __float_as_uint(x);
    unsigned r = (u + 0x7FFFu + ((u >> 16) & 1u)) >> 16;
    return (short)r;
}
// monotone float->u32 (order-preserving, incl. negatives)
__device__ __forceinline__ unsigned mono(float f) {
    int b = __float_as_int(f);
    return (unsigned)(b ^ ((b >> 31) | 0x80000000));
}
__device__ __forceinline__ float demono(unsigned u) {
    int b = (u >> 31) ? (int)(u ^ 0x80000000u) : (int)~u;
    return __int_as_float(b);
}

// async global->LDS, 16B per lane; LDS dest = wave-uniform base + lane*16
__device__ __forceinline__ void gll16(const void* g, void* l) {
    __builtin_amdgcn_global_load_lds(
        (const __attribute__((address_space(1))) unsigned*)g,
        (__attribute__((address_space(3))) unsigned*)l, 16, 0, 0);
}

// ---------------------------------------------------------------------------
// P1: inverse row norms of embedding. 4 rows/block, one wave per row.
// ---------------------------------------------------------------------------
__global__ void invnorm_kernel(const float* __restrict__ emb, float* __restrict__ invn) {
    int wave = threadIdx.x >> 6;
    int lane = threadIdx.x & 63;
    int row  = blockIdx.x * 4 + wave;
    float v = emb[row * DIMS + lane];
    float s = v * v;
    #pragma unroll
    for (int off = 1; off < 64; off <<= 1) s += __shfl_xor(s, off, 64);
    if (lane == 0) invn[row] = 1.0f / sqrtf(s);
}

// ---------------------------------------------------------------------------
// P2: build B fragments for 32x32x16 MFMA:
//  ef[(ct*4+s)*64 + lane] = 8 bf16 of
//    en[code = ct*32 + (lane&31)][k = s*16 + (lane>>5)*8 + j]
// A and B use the SAME (lane,j)->k bijection -> contraction invariant.
// ---------------------------------------------------------------------------
__global__ void en_frag_kernel(const float* __restrict__ emb, const float* __restrict__ invn,
                               v8s* __restrict__ ef) {
    int ch = blockIdx.x * 256 + threadIdx.x;      // 0..65535
    int l  = ch & 63;
    int s  = (ch >> 6) & 3;
    int ct = ch >> 8;
    int code = ct * 32 + (l & 31);
    int kb   = s * 16 + (l >> 5) * 8;
    float rn = invn[code];
    v8s o;
    #pragma unroll
    for (int j = 0; j < 8; ++j) o[j] = bf16_rne(emb[code * DIMS + kb + j] * rn);
    ef[ch] = o;
}

// ---------------------------------------------------------------------------
// P3: z -> z_tok (fp32 token-major, exact rescore)  +  A fragments (32x32).
// Block = one (b,h) row = 64 tokens = 2 m-tiles of 32.
// ---------------------------------------------------------------------------
__global__ __launch_bounds__(256)
void z_prep_kernel(const float* __restrict__ z, float* __restrict__ z_tok,
                   v8s* __restrict__ af) {
    __shared__ float zs[64][65];   // [c][token_local], +1 pad
    __shared__ float part[4][64];
    __shared__ float rn[64];
    const int tid = threadIdx.x;
    const int w   = tid & 63;
    const int cg  = tid >> 6;
    const int bh  = blockIdx.x;            // 0..511
    const int b   = bh >> 6, h = bh & 63;

    const float* zb = z + (size_t)b * (C_ * H_ * W_) + h * W_;
    float ss = 0.f;
    #pragma unroll
    for (int cc = 0; cc < 16; ++cc) {
        int c = cg * 16 + cc;
        float v = zb[c * (H_ * W_) + w];
        zs[c][w] = v;
        ss += v * v;
    }
    part[cg][w] = ss;
    __syncthreads();
    if (tid < 64) {
        float s = part[0][tid] + part[1][tid] + part[2][tid] + part[3][tid];
        rn[tid] = 1.0f / sqrtf(s);
    }
    __syncthreads();

    // z_tok[t][c], coalesced in c
    {
        int c  = tid & 63;
        int tg = tid >> 6;
        #pragma unroll
        for (int i = 0; i < 16; ++i) {
            int tloc = tg * 16 + i;
            z_tok[(size_t)(bh * 64 + tloc) * DIMS + c] = zs[c][tloc];
        }
    }
    // A fragments: 2 mtiles x 4 ksteps x 64 lanes = 512 chunks, 2/thread
    #pragma unroll
    for (int ii = 0; ii < 2; ++ii) {
        int ch  = tid + ii * 256;
        int mtl = ch >> 8;            // 0..1
        int s   = (ch >> 6) & 3;
        int l   = ch & 63;
        int tloc = mtl * 32 + (l & 31);
        int kb   = s * 16 + (l >> 5) * 8;
        float rr = rn[tloc];
        v8s o;
        #pragma unroll
        for (int j = 0; j < 8; ++j) o[j] = bf16_rne(zs[kb + j][tloc] * rr);
        af[(size_t)((bh * 2 + mtl) * 4 + s) * 64 + l] = o;
    }
}

// ---------------------------------------------------------------------------
// pass1f: 32x32x16 MFMA scan + atomic-free candidate append, 2-way code split.
//  256 thr (4 waves), 1 m-tile(32 tok)/wave -> 128 tokens/block.
//  Grid = 256 m-groups x 2 splits = 512 blocks (2/CU, 8 waves/CU).
//  Split scans 4096 codes: 16 chunks of 256 codes (8 code-tiles), 2x32KB LDS
//  dbuf via global_load_lds. Chunk 0 warm (max only), re-scanned at end.
//  Per-split cand/cnt/tokmax -> plain stores, no atomics (wave owns token).
// ---------------------------------------------------------------------------
#define CT_CHUNK 8
#define NCHUNKS 16
#define CHUNK_BYTES (CT_CHUNK * 4 * 64 * 16)   // 32768

__device__ __forceinline__ void stage_chunk(const char* g, char* l, int wave, int lane) {
    #pragma unroll
    for (int i = 0; i < 8; ++i) {
        int unit = wave * 8 + i;
        gll16(g + unit * 1024 + lane * 16, l + unit * 1024);
    }
}

__global__ __launch_bounds__(256, 2)
void pass1f_kernel(const v8s* __restrict__ af, const v8s* __restrict__ ef,
                   unsigned* __restrict__ tokmax0, unsigned* __restrict__ tokmax1,
                   unsigned* __restrict__ cnt0, unsigned* __restrict__ cnt1,
                   unsigned long long* __restrict__ cand0,
                   unsigned long long* __restrict__ cand1, int slots) {
    __shared__ v8s lds[2][CT_CHUNK * 4 * 64];   // 2 x 32 KB
    const int tid  = threadIdx.x;
    const int lane = tid & 63;
    const int wave = tid >> 6;
    const int split = blockIdx.x & 1;
    const int mtile = (blockIdx.x >> 1) * 4 + wave;   // 0..1023
    const int g    = lane >> 5;
    const int col  = lane & 31;

    unsigned* tokmax = split ? tokmax1 : tokmax0;
    unsigned* cnt    = split ? cnt1    : cnt0;
    unsigned long long* cand = split ? cand1 : cand0;

    v8s a[4];
    #pragma unroll
    for (int s = 0; s < 4; ++s) a[s] = af[(size_t)(mtile * 4 + s) * 64 + lane];

    float mx[16], thr[16];
    int cn[16];
    #pragma unroll
    for (int r = 0; r < 16; ++r) { mx[r] = -1e30f; thr[r] = 1e30f; cn[r] = 0; }

    const char* gbase = (const char*)ef + (size_t)split * 128 * 4096;  // 128 ctiles
    stage_chunk(gbase, (char*)lds[0], wave, lane);

    // process one chunk's 8 code-tiles (32 codes each)
    auto process = [&](const v8s* buf, int ctile, bool append) {
        for (int j = 0; j < CT_CHUNK; ++j) {
            v8s b0 = buf[(j * 4 + 0) * 64 + lane];
            v8s b1 = buf[(j * 4 + 1) * 64 + lane];
            v8s b2 = buf[(j * 4 + 2) * 64 + lane];
            v8s b3 = buf[(j * 4 + 3) * 64 + lane];
            v16f t = (v16f)(0.f);
            t = __builtin_amdgcn_mfma_f32_32x32x16_bf16(a[0], b0, t, 0, 0, 0);
            t = __builtin_amdgcn_mfma_f32_32x32x16_bf16(a[1], b1, t, 0, 0, 0);
            t = __builtin_amdgcn_mfma_f32_32x32x16_bf16(a[2], b2, t, 0, 0, 0);
            t = __builtin_amdgcn_mfma_f32_32x32x16_bf16(a[3], b3, t, 0, 0, 0);
            if (append) {
                unsigned pm = 0;
                #pragma unroll
                for (int r = 0; r < 16; ++r)
                    pm |= (t[r] >= thr[r]) ? (1u << r) : 0u;
                if (__ballot(pm != 0)) {             // ONE ballot; rare branch
                    #pragma unroll
                    for (int r = 0; r < 16; ++r) {
                        unsigned long long m = __ballot((pm >> r) & 1);
                        if (m) {
                            unsigned qm = (unsigned)(m >> (g * 32));
                            int base = cn[r];
                            cn[r] = base + __popc(qm);   // 32-group consistent
                            if ((pm >> r) & 1) {
                                int slot = base + __popc(qm & ((1u << col) - 1u));
                                if (slot < slots) {
                                    int row  = (r & 3) + 8 * (r >> 2) + 4 * g;
                                    int tok  = mtile * 32 + row;
                                    int code = (ctile + j) * 32 + col;
                                    cand[(size_t)tok * slots + slot] =
                                        ((unsigned long long)mono(t[r]) << 32) | (unsigned)code;
                                }
                            }
                        }
                    }
                }
            }
            #pragma unroll
            for (int r = 0; r < 16; ++r) mx[r] = fmaxf(mx[r], t[r]);
        }
    };

    const int ctile0 = split * 128;
    for (int c = 0; c < NCHUNKS; ++c) {
        __syncthreads();    // drains this wave's outstanding global_load_lds
        if (c + 1 < NCHUNKS)
            stage_chunk(gbase + (size_t)(c + 1) * CHUNK_BYTES,
                        (char*)lds[(c + 1) & 1], wave, lane);
        if (c == 0) process(lds[0], ctile0, false);          // warm: max only
        else        process(lds[c & 1], ctile0 + c * CT_CHUNK, true);
        // cross-column (32 code-cols) running max -> threshold
        #pragma unroll
        for (int r = 0; r < 16; ++r) {
            float v = mx[r];
            v = fmaxf(v, __shfl_xor(v, 1, 64));
            v = fmaxf(v, __shfl_xor(v, 2, 64));
            v = fmaxf(v, __shfl_xor(v, 4, 64));
            v = fmaxf(v, __shfl_xor(v, 8, 64));
            v = fmaxf(v, __shfl_xor(v, 16, 64));
            mx[r]  = v;
            thr[r] = v - MARGIN;
        }
    }

    // re-scan chunk 0 (was warm) against the final threshold
    __syncthreads();
    stage_chunk(gbase, (char*)lds[0], wave, lane);
    __syncthreads();
    process(lds[0], ctile0, true);

    // publish per-token bf16 max + candidate count (plain stores)
    if (col == 0) {
        #pragma unroll
        for (int r = 0; r < 16; ++r) {
            int row = (r & 3) + 8 * (r >> 2) + 4 * g;
            int tok = mtile * 32 + row;
            tokmax[tok] = mono(mx[r]);
            cnt[tok]    = (unsigned)cn[r];
        }
    }
}

// ---------------------------------------------------------------------------
// filter: merge both splits' candidate lists; LANE-PER-CANDIDATE exact fp32
// rescore (z row broadcast from LDS), u64 shuffle-tree argmax (tie -> lowest
// code). Wave handles 16 tokens. Overflow tokens -> fallback list.
// ---------------------------------------------------------------------------
__global__ __launch_bounds__(256)
void filter_kernel(const unsigned long long* __restrict__ cand0,
                   const unsigned long long* __restrict__ cand1,
                   const unsigned* __restrict__ cnt0, const unsigned* __restrict__ cnt1,
                   const unsigned* __restrict__ tm0, const unsigned* __restrict__ tm1,
                   const float* __restrict__ z_tok, const float* __restrict__ emb,
                   const float* __restrict__ invn, int slots,
                   int* __restrict__ idx, float* __restrict__ idxmap,
                   int* __restrict__ ovflist, unsigned* __restrict__ ovfcnt) {
    __shared__ float zrow[4][64];
    const int lane = threadIdx.x & 63;
    const int wave = threadIdx.x >> 6;
    const int wid  = blockIdx.x * 4 + wave;   // 0..2047
    for (int k = 0; k < 16; ++k) {
        const int t = wid * 16 + k;
        int c0 = (int)cnt0[t], c1 = (int)cnt1[t];
        if (c0 > slots || c1 > slots) {
            if (lane == 0) { unsigned s = atomicAdd(ovfcnt, 1u); ovflist[s] = t; }
            continue;
        }
        float thrf = fmaxf(demono(tm0[t]), demono(tm1[t])) - MARGIN;
        if (lane < 16)
            ((float4*)zrow[wave])[lane] = ((const float4*)(z_tok + (size_t)t * DIMS))[lane];
        int total = c0 + c1;                      // <= 32
        unsigned long long e = 0;
        if (lane < c0)          e = cand0[(size_t)t * slots + lane];
        else if (lane < total)  e = cand1[(size_t)t * slots + (lane - c0)];
        unsigned long long key = 0;
        if (lane < total && demono((unsigned)(e >> 32)) >= thrf) {
            int code = (int)(e & 0xFFFFFFFFull);
            const float4* e4 = (const float4*)(emb + (size_t)code * DIMS);
            const float4* z4 = (const float4*)zrow[wave];
            float s0 = 0.f, s1 = 0.f, s2 = 0.f, s3 = 0.f;
            #pragma unroll
            for (int q = 0; q < 16; ++q) {
                float4 ee = e4[q]; float4 zz = z4[q];
                s0 += zz.x * ee.x; s1 += zz.y * ee.y;
                s2 += zz.z * ee.z; s3 += zz.w * ee.w;
            }
            float d = ((s0 + s1) + (s2 + s3)) * invn[code];
            key = ((unsigned long long)mono(d) << 32) | (0xFFFFFFFFu - (unsigned)code);
        }
        #pragma unroll
        for (int off = 32; off; off >>= 1) {
            unsigned long long o = __shfl_xor(key, off, 64);
            if (o > key) key = o;
        }
        if (lane == 0) {
            unsigned code = 0xFFFFFFFFu - (unsigned)(key & 0xFFFFFFFFull);
            idx[t] = (int)code;
            idxmap[t] = (float)code;
        }
    }
}

// ---------------------------------------------------------------------------
// fallback: exact brute force for overflow tokens — one BLOCK per token,
// 256 threads x 32 codes each, float4 dot vs LDS z row, LDS tree-reduce.
// ---------------------------------------------------------------------------
__global__ __launch_bounds__(256)
void fallback_kernel(const int* __restrict__ ovflist, const unsigned* __restrict__ ovfcnt,
                     const float* __restrict__ z_tok, const float* __restrict__ emb,
                     const float* __restrict__ invn,
                     int* __restrict__ idx, float* __restrict__ idxmap) {
    __shared__ float zsh[64];
    __shared__ unsigned long long red[256];
    const int tid = threadIdx.x;
    const int nt = (int)*ovfcnt;
    for (int u = blockIdx.x; u < nt; u += gridDim.x) {
        const int t = ovflist[u];
        if (tid < 64) zsh[tid] = z_tok[(size_t)t * DIMS + tid];
        __syncthreads();
        unsigned long long best = 0;
        for (int code = tid; code < NUM_EMBED; code += 256) {
            const float4* e4 = (const float4*)(emb + (size_t)code * DIMS);
            const float4* z4 = (const float4*)zsh;
            float s0 = 0.f, s1 = 0.f, s2 = 0.f, s3 = 0.f;
            #pragma unroll
            for (int q = 0; q < 16; ++q) {
                float4 e = e4[q]; float4 zz = z4[q];
                s0 += zz.x * e.x; s1 += zz.y * e.y;
                s2 += zz.z * e.z; s3 += zz.w * e.w;
            }
            float d = ((s0 + s1) + (s2 + s3)) * invn[code];
            unsigned long long pk = ((unsigned long long)mono(d) << 32) |
                                    (0xFFFFFFFFu - (unsigned)code);
            if (pk > best) best = pk;
        }
        red[tid] = best;
        __syncthreads();
        for (int s = 128; s > 0; s >>= 1) {
            if (tid < s && red[tid + s] > red[tid]) red[tid] = red[tid + s];
            __syncthreads();
        }
        if (tid == 0) {
            unsigned code = 0xFFFFFFFFu - (unsigned)(red[0] & 0xFFFFFFFFull);
            idx[t] = (int)code;
            idxmap[t] = (float)code;
        }
        __syncthreads();
    }
}

// ---------------------------------------------------------------------------
// K3: gather z_q, out = zv + (q - zv), SSE partial, histogram.
// ---------------------------------------------------------------------------
__global__ void gather_loss_kernel(const float* __restrict__ z,
                                   const float* __restrict__ emb,
                                   const int* __restrict__ idx,
                                   float* __restrict__ out,
                                   float* __restrict__ partial,
                                   int* __restrict__ hist) {
    __shared__ float red[256];
    const int tid  = threadIdx.x;
    const int lane = tid & 63;   // w
    const int wave = tid >> 6;
    const int bt   = blockIdx.x; // 0..511
    const int b    = bt >> 6;
    const int h    = bt & 63;

    const int t  = bt * 64 + lane;
    const int id = idx[t];
    const long base = (long)b * (C_ * H_ * W_) + h * W_ + lane;

    float sse = 0.f;
    #pragma unroll
    for (int cc = 0; cc < 16; ++cc) {
        const int c = wave * 16 + cc;
        const float q  = emb[id * DIMS + c];
        const float zv = z[base + (long)c * (H_ * W_)];
        out[base + (long)c * (H_ * W_)] = zv + (q - zv);  // exact ref expression
        const float d = q - zv;
        sse += d * d;
    }

    red[tid] = sse;
    __syncthreads();
    for (int s = 128; s > 0; s >>= 1) {
        if (tid < s) red[tid] += red[tid + s];
        __syncthreads();
    }
    if (tid == 0) partial[bt] = red[0];
    if (wave == 0) atomicAdd(&hist[id], 1);
}

// ---------------------------------------------------------------------------
// K4: finalize loss + perplexity. One block of 256 threads.
// ---------------------------------------------------------------------------
__global__ void finalize_kernel(const float* __restrict__ partial,
                                const int* __restrict__ hist,
                                float* __restrict__ out_scal) {
    __shared__ double red[256];
    const int tid = threadIdx.x;

    double s = 0.0;
    for (int i = tid; i < 512; i += 256) s += (double)partial[i];
    red[tid] = s;
    __syncthreads();
    for (int st = 128; st > 0; st >>= 1) {
        if (tid < st) red[tid] += red[tid + st];
        __syncthreads();
    }
    const double sse = red[0];
    __syncthreads();

    double e = 0.0;
    for (int k = tid; k < NUM_EMBED; k += 256) {
        float p = (float)hist[k] / (float)N_TOK;
        e += (double)(p * logf(p + 1e-10f));
    }
    red[tid] = e;
    __syncthreads();
    for (int st = 128; st > 0; st >>= 1) {
        if (tid < st) red[tid] += red[tid + st];
        __syncthreads();
    }
    if (tid == 0) {
        out_scal[0] = (float)(1.25 * sse / (double)N_ELEM);
        out_scal[1] = expf(-(float)red[0]);
    }
}

// ---------------------------------------------------------------------------
extern "C" void kernel_launch(void* const* d_in, const int* in_sizes, int n_in,
                              void* d_out, int out_size, void* d_ws, size_t ws_size,
                              hipStream_t stream) {
    const float* z   = (const float*)d_in[0];
    const float* emb = (const float*)d_in[1];
    float* o = (float*)d_out;

    // workspace layout (static ~6.1 MB; cand sized from ws_size)
    char* ws = (char*)d_ws;
    v8s*  af      = (v8s*)ws;                                        // 4 MB
    v8s*  ef      = (v8s*)(ws + 4194304);                            // 1 MB
    unsigned* tokmax0 = (unsigned*)(ws + 5242880);                   // 128 KB
    unsigned* tokmax1 = (unsigned*)(ws + 5373952);                   // 128 KB
    unsigned* cnt0    = (unsigned*)(ws + 5505024);                   // 128 KB
    unsigned* cnt1    = (unsigned*)(ws + 5636096);                   // 128 KB
    int*   idx     = (int*)(ws + 5767168);                           // 128 KB
    float* invn    = (float*)(ws + 5898240);                         // 32 KB
    float* partial = (float*)(ws + 5931008);                         // 4 KB
    // ---- zeroed region: hist | ovfcnt (contiguous) ----
    int*   hist    = (int*)(ws + 5935104);                           // 32 KB
    unsigned* ovfcnt = (unsigned*)(ws + 5967872);                    // 256 B
    int*   ovflist = (int*)(ws + 5968128);                           // 128 KB
    unsigned long long* cand0 = (unsigned long long*)(ws + 6099200);

    // candidate slots per token per split, sized from remaining workspace
    long long avail = (long long)ws_size - 6099200;
    int slots = (int)(avail / (2LL * N_TOK * 8));
    if (slots > 16) slots = 16;
    if (slots < 0)  slots = 0;
    unsigned long long* cand1 = cand0 + (size_t)N_TOK * slots;

    float* out_q      = o;                  // 2097152 floats
    float* out_scal   = o + N_ELEM;         // loss, perplexity
    float* out_idxmap = o + N_ELEM + 2;     // 32768 floats
    float* z_tok      = o;                  // out_q region reused as fp32 token-major
                                            // scratch; overwritten by gather later

    hipMemsetAsync(hist, 0, 5968128 - 5935104, stream);  // hist|ovfcnt

    invnorm_kernel<<<NUM_EMBED / 4, 256, 0, stream>>>(emb, invn);
    en_frag_kernel<<<256, 256, 0, stream>>>(emb, invn, ef);
    z_prep_kernel<<<512, 256, 0, stream>>>(z, z_tok, af);
    pass1f_kernel<<<512, 256, 0, stream>>>(af, ef, tokmax0, tokmax1, cnt0, cnt1,
                                           cand0, cand1, slots);
    filter_kernel<<<512, 256, 0, stream>>>(cand0, cand1, cnt0, cnt1, tokmax0, tokmax1,
                                           z_tok, emb, invn, slots,
                                           idx, out_idxmap, ovflist, ovfcnt);
    fallback_kernel<<<256, 256, 0, stream>>>(ovflist, ovfcnt, z_tok, emb, invn,
                                             idx, out_idxmap);
    gather_loss_kernel<<<N_TOK / 64, 256, 0, stream>>>(z, emb, idx, out_q, partial, hist);
    finalize_kernel<<<1, 256, 0, stream>>>(partial, hist, out_scal);
}

// Round 8
// 267.696 us; speedup vs baseline: 1.2318x; 1.2318x over previous
//
#include <hip/hip_runtime.h>
#include <hip/hip_bf16.h>
#include <math.h>

// Problem constants
#define B_    8
#define C_    64
#define H_    64
#define W_    64
#define NUM_EMBED 8192
#define DIMS  64
#define N_TOK (B_ * H_ * W_)           // 32768
#define N_ELEM (B_ * C_ * H_ * W_)     // 2097152

typedef short v8s __attribute__((ext_vector_type(8)));   // 8 bf16 = 4 VGPR
typedef float v4f __attribute__((ext_vector_type(4)));   // MFMA acc

#define MARGIN 0.0095f  // rigorous bf16 bound 2*2^-8 = 0.0078, + headroom
#define SPLITS 4

// ---- helpers ---------------------------------------------------------------
__device__ __forceinline__ short bf16_rne(float x) {
    unsigned u = __float_as_uint(x);
    unsigned r = (u + 0x7FFFu + ((u >> 16) & 1u)) >> 16;
    return (short)r;
}
// monotone float->u32 (order-preserving, incl. negatives)
__device__ __forceinline__ unsigned mono(float f) {
    int b = __float_as_int(f);
    return (unsigned)(b ^ ((b >> 31) | 0x80000000));
}
__device__ __forceinline__ float demono(unsigned u) {
    int b = (u >> 31) ? (int)(u ^ 0x80000000u) : (int)~u;
    return __int_as_float(b);
}

// async global->LDS, 16B per lane; LDS dest = wave-uniform base + lane*16
__device__ __forceinline__ void gll16(const void* g, void* l) {
    __builtin_amdgcn_global_load_lds(
        (const __attribute__((address_space(1))) unsigned*)g,
        (__attribute__((address_space(3))) unsigned*)l, 16, 0, 0);
}

// ---------------------------------------------------------------------------
// prep_cb: fused invnorm + en_frag (16x16 layout, byte-identical to R2-R6's)
// + zero hist/ovfcnt. One wave per codebook row; lane == k exactly:
//   k = st*32 + quad*8 + jj  with st=lane>>5, quad=(lane>>3)&3, jj=lane&7.
// dest: ((short*)ef)[ ((ct*2+st)*64 + quad*16 + cl)*8 + jj ],  ct=row>>4, cl=row&15
// ---------------------------------------------------------------------------
__global__ __launch_bounds__(256)
void prep_cb_kernel(const float* __restrict__ emb, float* __restrict__ invn,
                    short* __restrict__ ef, int* __restrict__ hist,
                    unsigned* __restrict__ ovfcnt) {
    const int tid  = threadIdx.x;
    const int wave = tid >> 6;
    const int lane = tid & 63;
    const int row  = blockIdx.x * 4 + wave;

    float v = emb[row * DIMS + lane];
    float s = v * v;
    #pragma unroll
    for (int off = 1; off < 64; off <<= 1) s += __shfl_xor(s, off, 64);
    float rn = 1.0f / sqrtf(s);
    if (lane == 0) invn[row] = rn;

    int ct = row >> 4, cl = row & 15;
    int st = lane >> 5, quad = (lane >> 3) & 3, jj = lane & 7;
    ef[(size_t)(((ct * 2 + st) * 64) + quad * 16 + cl) * 8 + jj] = bf16_rne(v * rn);

    if (tid < 4) hist[blockIdx.x * 4 + tid] = 0;
    if (blockIdx.x == 0 && tid == 0) *ovfcnt = 0;
}

// ---------------------------------------------------------------------------
// z_prep: z -> z_tok (fp32 token-major) + A fragments (16x16 layout).
// ---------------------------------------------------------------------------
__global__ __launch_bounds__(256)
void z_prep_kernel(const float* __restrict__ z, float* __restrict__ z_tok,
                   v8s* __restrict__ af) {
    __shared__ float zs[64][65];   // [c][token_local], +1 pad
    __shared__ float part[4][64];
    __shared__ float rn[64];
    const int tid = threadIdx.x;
    const int w   = tid & 63;
    const int cg  = tid >> 6;
    const int bh  = blockIdx.x;            // 0..511
    const int b   = bh >> 6, h = bh & 63;

    const float* zb = z + (size_t)b * (C_ * H_ * W_) + h * W_;
    float ss = 0.f;
    #pragma unroll
    for (int cc = 0; cc < 16; ++cc) {
        int c = cg * 16 + cc;
        float v = zb[c * (H_ * W_) + w];
        zs[c][w] = v;
        ss += v * v;
    }
    part[cg][w] = ss;
    __syncthreads();
    if (tid < 64) {
        float s = part[0][tid] + part[1][tid] + part[2][tid] + part[3][tid];
        rn[tid] = 1.0f / sqrtf(s);
    }
    __syncthreads();

    {
        int c  = tid & 63;
        int tg = tid >> 6;
        #pragma unroll
        for (int i = 0; i < 16; ++i) {
            int tloc = tg * 16 + i;
            z_tok[(size_t)(bh * 64 + tloc) * DIMS + c] = zs[c][tloc];
        }
    }
    #pragma unroll
    for (int ii = 0; ii < 2; ++ii) {
        int ch  = tid + ii * 256;
        int mtl = ch >> 7;
        int st  = (ch >> 6) & 1;
        int l   = ch & 63;
        int tloc = mtl * 16 + (l & 15);
        int kb   = st * 32 + ((l >> 4) & 3) * 8;
        float rr = rn[tloc];
        v8s o;
        #pragma unroll
        for (int j = 0; j < 8; ++j) o[j] = bf16_rne(zs[kb + j][tloc] * rr);
        af[(size_t)((bh * 4 + mtl) * 2 + st) * 64 + l] = o;
    }
}

// ---------------------------------------------------------------------------
// pass1f: 16x16x32 MFMA scan, RT=2, 4-way code split, atomic-free append.
//  256 thr (4 waves), 2 m-tiles/wave -> 128 tokens/block.
//  Grid = 256 m-groups x 4 splits = 1024 blocks -> 4 blocks/CU, 16 waves/CU.
//  Split scans 2048 codes: 16 chunks of 128 codes (8 tiles), 2x16KB LDS dbuf.
//  First 2 chunks warm (max only), re-scanned at end vs final threshold.
//  Detection: per-lane tree-max over 8 acc regs vs per-lane thrmin (min of
//  the lane's 8 thresholds) -> 1 cmp + 1 ballot; exact per-reg check inside.
// ---------------------------------------------------------------------------
#define CT_CHUNK 8
#define NCHUNKS 16
#define WARM 2
#define CHUNK_BYTES (CT_CHUNK * 2 * 64 * 16)   // 16384

__device__ __forceinline__ void stage_chunk(const char* g, char* l, int wave, int lane) {
    #pragma unroll
    for (int i = 0; i < 4; ++i) {
        int unit = wave * 4 + i;
        gll16(g + unit * 1024 + lane * 16, l + unit * 1024);
    }
}

__global__ __launch_bounds__(256, 4)
void pass1f_kernel(const v8s* __restrict__ af, const v8s* __restrict__ ef,
                   unsigned* __restrict__ tokmax, unsigned* __restrict__ cnt,
                   unsigned long long* __restrict__ cand, int slots) {
    __shared__ v8s lds[2][CT_CHUNK * 2 * 64];   // 2 x 16 KB
    const int tid  = threadIdx.x;
    const int lane = tid & 63;
    const int wave = tid >> 6;
    const int quad = lane >> 4;
    const int col  = lane & 15;
    const int mgrp  = blockIdx.x >> 2;          // 0..255
    const int split = blockIdx.x & 3;
    const int mtb   = mgrp * 8 + wave * 2;      // first of this wave's 2 m-tiles

    v8s a[2][2];
    #pragma unroll
    for (int r = 0; r < 2; ++r)
        #pragma unroll
        for (int s = 0; s < 2; ++s)
            a[r][s] = af[(size_t)((mtb + r) * 2 + s) * 64 + lane];

    float mx[8], thr[8];
    int cn[8];
    #pragma unroll
    for (int i = 0; i < 8; ++i) { mx[i] = -1e30f; thr[i] = 1e30f; cn[i] = 0; }
    float thrmin = 1e30f;

    const char* gbase = (const char*)ef + (size_t)split * 2048 * 128;  // 128 B/code
    const int ctile0 = split * 128;
    unsigned* tm_s  = tokmax + (size_t)split * N_TOK;
    unsigned* cnt_s = cnt    + (size_t)split * N_TOK;

    stage_chunk(gbase, (char*)lds[0], wave, lane);

    auto process = [&](const v8s* buf, int ctile, bool append) {
        #pragma unroll 2
        for (int j = 0; j < CT_CHUNK; ++j) {
            v8s b0 = buf[(j * 2 + 0) * 64 + lane];
            v8s b1 = buf[(j * 2 + 1) * 64 + lane];
            v4f t0 = (v4f){0.f, 0.f, 0.f, 0.f};
            v4f t1 = (v4f){0.f, 0.f, 0.f, 0.f};
            t0 = __builtin_amdgcn_mfma_f32_16x16x32_bf16(a[0][0], b0, t0, 0, 0, 0);
            t0 = __builtin_amdgcn_mfma_f32_16x16x32_bf16(a[0][1], b1, t0, 0, 0, 0);
            t1 = __builtin_amdgcn_mfma_f32_16x16x32_bf16(a[1][0], b0, t1, 0, 0, 0);
            t1 = __builtin_amdgcn_mfma_f32_16x16x32_bf16(a[1][1], b1, t1, 0, 0, 0);
            if (append) {
                // cheap detect: tree-max of 8 regs vs per-lane thrmin
                float m01 = fmaxf(fmaxf(t0[0], t0[1]), fmaxf(t0[2], t0[3]));
                float m23 = fmaxf(fmaxf(t1[0], t1[1]), fmaxf(t1[2], t1[3]));
                float bm  = fmaxf(m01, m23);
                if (__ballot(bm >= thrmin)) {          // rare, wave-uniform
                    #pragma unroll
                    for (int r = 0; r < 2; ++r)
                        #pragma unroll
                        for (int i = 0; i < 4; ++i) {
                            float v = r ? t1[i] : t0[i];
                            bool cond = (v >= thr[r * 4 + i]);
                            unsigned long long m = __ballot(cond);
                            if (m) {
                                unsigned qm = (unsigned)((m >> (quad * 16)) & 0xFFFFull);
                                int base = cn[r * 4 + i];
                                cn[r * 4 + i] = base + __popc(qm);
                                if (cond) {
                                    int slot = base + __popc(qm & ((1u << col) - 1u));
                                    if (slot < slots) {
                                        int tok  = (mtb + r) * 16 + quad * 4 + i;
                                        int code = (ctile + j) * 16 + col;
                                        cand[(size_t)(split * N_TOK + tok) * slots + slot] =
                                            ((unsigned long long)mono(v) << 32) | (unsigned)code;
                                    }
                                }
                            }
                        }
                }
            }
            #pragma unroll
            for (int i = 0; i < 4; ++i) {
                mx[i]     = fmaxf(mx[i],     t0[i]);
                mx[4 + i] = fmaxf(mx[4 + i], t1[i]);
            }
        }
    };

    for (int c = 0; c < NCHUNKS; ++c) {
        __syncthreads();    // drains this wave's outstanding global_load_lds
        if (c + 1 < NCHUNKS)
            stage_chunk(gbase + (size_t)(c + 1) * CHUNK_BYTES,
                        (char*)lds[(c + 1) & 1], wave, lane);
        process(lds[c & 1], ctile0 + c * CT_CHUNK, c >= WARM);
        // cross-column (16 code-cols) running max -> thresholds
        #pragma unroll
        for (int i = 0; i < 8; ++i) {
            float v = mx[i];
            v = fmaxf(v, __shfl_xor(v, 1, 64));
            v = fmaxf(v, __shfl_xor(v, 2, 64));
            v = fmaxf(v, __shfl_xor(v, 4, 64));
            v = fmaxf(v, __shfl_xor(v, 8, 64));
            mx[i]  = v;
            thr[i] = v - MARGIN;
        }
        float t01 = fminf(fminf(thr[0], thr[1]), fminf(thr[2], thr[3]));
        float t23 = fminf(fminf(thr[4], thr[5]), fminf(thr[6], thr[7]));
        thrmin = fminf(t01, t23);
    }

    // re-scan the 2 warm chunks against the final thresholds
    __syncthreads();
    stage_chunk(gbase, (char*)lds[0], wave, lane);
    stage_chunk(gbase + CHUNK_BYTES, (char*)lds[1], wave, lane);
    __syncthreads();
    process(lds[0], ctile0, true);
    process(lds[1], ctile0 + CT_CHUNK, true);

    // publish per-token bf16 max + candidate count (plain stores)
    if (col == 0) {
        #pragma unroll
        for (int r = 0; r < 2; ++r)
            #pragma unroll
            for (int i = 0; i < 4; ++i) {
                int tok = (mtb + r) * 16 + quad * 4 + i;
                tm_s[tok]  = mono(mx[r * 4 + i]);
                cnt_s[tok] = (unsigned)cn[r * 4 + i];
            }
    }
}

// ---------------------------------------------------------------------------
// filter: merge 4 splits' candidate lists; LANE-PER-CANDIDATE exact fp32
// rescore (float4 dot vs LDS z row — R7-proven formula), u64 shuffle-tree
// argmax (tie -> lowest code). Wave handles 16 tokens sequentially.
// ---------------------------------------------------------------------------
__global__ __launch_bounds__(256)
void filter_kernel(const unsigned long long* __restrict__ cand,
                   const unsigned* __restrict__ cnt, const unsigned* __restrict__ tokmax,
                   const float* __restrict__ z_tok, const float* __restrict__ emb,
                   const float* __restrict__ invn, int slots,
                   int* __restrict__ idx, float* __restrict__ idxmap,
                   int* __restrict__ ovflist, unsigned* __restrict__ ovfcnt) {
    __shared__ float zrow[4][64];
    const int lane = threadIdx.x & 63;
    const int wave = threadIdx.x >> 6;
    const int wid  = blockIdx.x * 4 + wave;   // 0..2047
    for (int k = 0; k < 16; ++k) {
        const int t = wid * 16 + k;
        int c0 = (int)cnt[0 * N_TOK + t], c1 = (int)cnt[1 * N_TOK + t];
        int c2 = (int)cnt[2 * N_TOK + t], c3 = (int)cnt[3 * N_TOK + t];
        if (c0 > slots || c1 > slots || c2 > slots || c3 > slots) {
            if (lane == 0) { unsigned s = atomicAdd(ovfcnt, 1u); ovflist[s] = t; }
            continue;
        }
        float thrf = fmaxf(fmaxf(demono(tokmax[0 * N_TOK + t]), demono(tokmax[1 * N_TOK + t])),
                           fmaxf(demono(tokmax[2 * N_TOK + t]), demono(tokmax[3 * N_TOK + t])))
                     - MARGIN;
        if (lane < 16)
            ((float4*)zrow[wave])[lane] = ((const float4*)(z_tok + (size_t)t * DIMS))[lane];
        int p0 = c0, p1 = c0 + c1, p2 = p1 + c2, total = p2 + c3;  // <= 4*slots
        unsigned long long e = 0;
        if (lane < total) {
            int s, off;
            if      (lane < p0) { s = 0; off = lane; }
            else if (lane < p1) { s = 1; off = lane - p0; }
            else if (lane < p2) { s = 2; off = lane - p1; }
            else                { s = 3; off = lane - p2; }
            e = cand[(size_t)(s * N_TOK + t) * slots + off];
        }
        unsigned long long key = 0;
        if (lane < total && demono((unsigned)(e >> 32)) >= thrf) {
            int code = (int)(e & 0xFFFFFFFFull);
            const float4* e4 = (const float4*)(emb + (size_t)code * DIMS);
            const float4* z4 = (const float4*)zrow[wave];
            float s0 = 0.f, s1 = 0.f, s2 = 0.f, s3 = 0.f;
            #pragma unroll
            for (int q = 0; q < 16; ++q) {
                float4 ee = e4[q]; float4 zz = z4[q];
                s0 += zz.x * ee.x; s1 += zz.y * ee.y;
                s2 += zz.z * ee.z; s3 += zz.w * ee.w;
            }
            float d = ((s0 + s1) + (s2 + s3)) * invn[code];
            key = ((unsigned long long)mono(d) << 32) | (0xFFFFFFFFu - (unsigned)code);
        }
        #pragma unroll
        for (int off = 32; off; off >>= 1) {
            unsigned long long o = __shfl_xor(key, off, 64);
            if (o > key) key = o;
        }
        if (lane == 0) {
            unsigned code = 0xFFFFFFFFu - (unsigned)(key & 0xFFFFFFFFull);
            idx[t] = (int)code;
            idxmap[t] = (float)code;
        }
    }
}

// ---------------------------------------------------------------------------
// fallback: exact brute force for overflow tokens — one BLOCK per token,
// 256 threads x 32 codes each, float4 dot vs LDS z row, LDS tree-reduce.
// ---------------------------------------------------------------------------
__global__ __launch_bounds__(256)
void fallback_kernel(const int* __restrict__ ovflist, const unsigned* __restrict__ ovfcnt,
                     const float* __restrict__ z_tok, const float* __restrict__ emb,
                     const float* __restrict__ invn,
                     int* __restrict__ idx, float* __restrict__ idxmap) {
    __shared__ float zsh[64];
    __shared__ unsigned long long red[256];
    const int tid = threadIdx.x;
    const int nt = (int)*ovfcnt;
    for (int u = blockIdx.x; u < nt; u += gridDim.x) {
        const int t = ovflist[u];
        if (tid < 64) zsh[tid] = z_tok[(size_t)t * DIMS + tid];
        __syncthreads();
        unsigned long long best = 0;
        for (int code = tid; code < NUM_EMBED; code += 256) {
            const float4* e4 = (const float4*)(emb + (size_t)code * DIMS);
            const float4* z4 = (const float4*)zsh;
            float s0 = 0.f, s1 = 0.f, s2 = 0.f, s3 = 0.f;
            #pragma unroll
            for (int q = 0; q < 16; ++q) {
                float4 e = e4[q]; float4 zz = z4[q];
                s0 += zz.x * e.x; s1 += zz.y * e.y;
                s2 += zz.z * e.z; s3 += zz.w * e.w;
            }
            float d = ((s0 + s1) + (s2 + s3)) * invn[code];
            unsigned long long pk = ((unsigned long long)mono(d) << 32) |
                                    (0xFFFFFFFFu - (unsigned)code);
            if (pk > best) best = pk;
        }
        red[tid] = best;
        __syncthreads();
        for (int s = 128; s > 0; s >>= 1) {
            if (tid < s && red[tid + s] > red[tid]) red[tid] = red[tid + s];
            __syncthreads();
        }
        if (tid == 0) {
            unsigned code = 0xFFFFFFFFu - (unsigned)(red[0] & 0xFFFFFFFFull);
            idx[t] = (int)code;
            idxmap[t] = (float)code;
        }
        __syncthreads();
    }
}

// ---------------------------------------------------------------------------
// K3: gather z_q, out = zv + (q - zv), SSE partial, histogram.
// ---------------------------------------------------------------------------
__global__ void gather_loss_kernel(const float* __restrict__ z,
                                   const float* __restrict__ emb,
                                   const int* __restrict__ idx,
                                   float* __restrict__ out,
                                   float* __restrict__ partial,
                                   int* __restrict__ hist) {
    __shared__ float red[256];
    const int tid  = threadIdx.x;
    const int lane = tid & 63;   // w
    const int wave = tid >> 6;
    const int bt   = blockIdx.x; // 0..511
    const int b    = bt >> 6;
    const int h    = bt & 63;

    const int t  = bt * 64 + lane;
    const int id = idx[t];
    const long base = (long)b * (C_ * H_ * W_) + h * W_ + lane;

    float sse = 0.f;
    #pragma unroll
    for (int cc = 0; cc < 16; ++cc) {
        const int c = wave * 16 + cc;
        const float q  = emb[id * DIMS + c];
        const float zv = z[base + (long)c * (H_ * W_)];
        out[base + (long)c * (H_ * W_)] = zv + (q - zv);  // exact ref expression
        const float d = q - zv;
        sse += d * d;
    }

    red[tid] = sse;
    __syncthreads();
    for (int s = 128; s > 0; s >>= 1) {
        if (tid < s) red[tid] += red[tid + s];
        __syncthreads();
    }
    if (tid == 0) partial[bt] = red[0];
    if (wave == 0) atomicAdd(&hist[id], 1);
}

// ---------------------------------------------------------------------------
// K4: finalize loss + perplexity. One block of 1024 threads.
// ---------------------------------------------------------------------------
__global__ __launch_bounds__(1024)
void finalize_kernel(const float* __restrict__ partial,
                     const int* __restrict__ hist,
                     float* __restrict__ out_scal) {
    __shared__ double red[1024];
    const int tid = threadIdx.x;

    double s = (tid < 512) ? (double)partial[tid] : 0.0;
    red[tid] = s;
    __syncthreads();
    for (int st = 512; st > 0; st >>= 1) {
        if (tid < st) red[tid] += red[tid + st];
        __syncthreads();
    }
    const double sse = red[0];
    __syncthreads();

    double e = 0.0;
    #pragma unroll
    for (int k = tid; k < NUM_EMBED; k += 1024) {
        float p = (float)hist[k] / (float)N_TOK;
        e += (double)(p * logf(p + 1e-10f));
    }
    red[tid] = e;
    __syncthreads();
    for (int st = 512; st > 0; st >>= 1) {
        if (tid < st) red[tid] += red[tid + st];
        __syncthreads();
    }
    if (tid == 0) {
        out_scal[0] = (float)(1.25 * sse / (double)N_ELEM);
        out_scal[1] = expf(-(float)red[0]);
    }
}

// ---------------------------------------------------------------------------
extern "C" void kernel_launch(void* const* d_in, const int* in_sizes, int n_in,
                              void* d_out, int out_size, void* d_ws, size_t ws_size,
                              hipStream_t stream) {
    const float* z   = (const float*)d_in[0];
    const float* emb = (const float*)d_in[1];
    float* o = (float*)d_out;

    // workspace layout (static ~6.6 MB; cand sized from ws_size)
    char* ws = (char*)d_ws;
    v8s*  af      = (v8s*)ws;                                        // 4 MB
    v8s*  ef      = (v8s*)(ws + 4194304);                            // 1 MB
    unsigned* tokmax = (unsigned*)(ws + 5242880);                    // 512 KB (4 splits)
    unsigned* cnt    = (unsigned*)(ws + 5767168);                    // 512 KB (4 splits)
    int*   idx     = (int*)(ws + 6291456);                           // 128 KB
    float* invn    = (float*)(ws + 6422528);                         // 32 KB
    float* partial = (float*)(ws + 6455296);                         // 4 KB
    int*   hist    = (int*)(ws + 6459392);                           // 32 KB
    unsigned* ovfcnt = (unsigned*)(ws + 6492160);                    // 256 B
    int*   ovflist = (int*)(ws + 6492416);                           // 128 KB
    unsigned long long* cand = (unsigned long long*)(ws + 6623488);

    // candidate slots per token per split (expected appends ~4/split)
    long long avail = (long long)ws_size - 6623488;
    int slots = (int)(avail / ((long long)SPLITS * N_TOK * 8));
    if (slots > 12) slots = 12;
    if (slots < 0)  slots = 0;

    float* out_q      = o;                  // 2097152 floats
    float* out_scal   = o + N_ELEM;         // loss, perplexity
    float* out_idxmap = o + N_ELEM + 2;     // 32768 floats
    float* z_tok      = o;                  // out_q region reused as fp32 token-major
                                            // scratch; overwritten by gather later

    prep_cb_kernel<<<NUM_EMBED / 4, 256, 0, stream>>>(emb, invn, (short*)ef, hist, ovfcnt);
    z_prep_kernel<<<512, 256, 0, stream>>>(z, z_tok, af);
    pass1f_kernel<<<1024, 256, 0, stream>>>(af, ef, tokmax, cnt, cand, slots);
    filter_kernel<<<512, 256, 0, stream>>>(cand, cnt, tokmax, z_tok, emb, invn,
                                           slots, idx, out_idxmap, ovflist, ovfcnt);
    fallback_kernel<<<256, 256, 0, stream>>>(ovflist, ovfcnt, z_tok, emb, invn,
                                             idx, out_idxmap);
    gather_loss_kernel<<<N_TOK / 64, 256, 0, stream>>>(z, emb, idx, out_q, partial, hist);
    finalize_kernel<<<1, 1024, 0, stream>>>(partial, hist, out_scal);
}